// Round 1
// baseline (8521.471 us; speedup 1.0000x reference)
//
#include <hip/hip_runtime.h>

// GCN: 4x GCNConv(relu) -> global_add_pool -> MLP(96->32 relu ->1)
// N=100000 nodes, E=1600000 edges, F=32, H=96, G=2048 graphs.
// All fp32. Strategy: dense GEMM per layer (W in LDS, broadcast reads),
// self-loop init, per-edge atomic scatter. Pool via atomics. Tiny MLP head.

#define HIDDEN 96

__global__ __launch_bounds__(256) void fill_ones(float* p, int n) {
    int i = blockIdx.x * 256 + threadIdx.x;
    if (i < n) p[i] = 1.0f;
}

__global__ __launch_bounds__(256) void zero_kernel(float* p, int n) {
    int i = blockIdx.x * 256 + threadIdx.x;
    if (i < n) p[i] = 0.0f;
}

__global__ __launch_bounds__(256) void deg_count(const int* __restrict__ dst,
                                                 float* __restrict__ deg, int E) {
    int e = blockIdx.x * 256 + threadIdx.x;
    if (e < E) atomicAdd(&deg[dst[e]], 1.0f);
}

__global__ __launch_bounds__(256) void rsqrt_kernel(float* p, int n) {
    int i = blockIdx.x * 256 + threadIdx.x;
    if (i < n) p[i] = rsqrtf(p[i]);   // deg >= 1 always (self-loop)
}

__global__ __launch_bounds__(256) void norm_kernel(const int* __restrict__ src,
                                                   const int* __restrict__ dst,
                                                   const float* __restrict__ dinv,
                                                   float* __restrict__ nrm, int E) {
    int e = blockIdx.x * 256 + threadIdx.x;
    if (e < E) nrm[e] = dinv[src[e]] * dinv[dst[e]];
}

// Y[n x 96] = act(X[n x K]) @ W[K x 96].  W staged in LDS; all lanes read the
// same LDS address per FMA -> broadcast, conflict-free. One row per thread,
// 24 float4 accumulators (96 outputs).
template <int K, bool RELU>
__global__ __launch_bounds__(256) void gemm_kernel(const float* __restrict__ X,
                                                   const float* __restrict__ W,
                                                   float* __restrict__ Y, int n) {
    __shared__ float wlds[K * HIDDEN];
    for (int idx = threadIdx.x; idx < K * HIDDEN; idx += 256) wlds[idx] = W[idx];
    __syncthreads();

    int row = blockIdx.x * 256 + threadIdx.x;
    if (row >= n) return;

    float4 acc[24];
#pragma unroll
    for (int j = 0; j < 24; j++) acc[j] = make_float4(0.f, 0.f, 0.f, 0.f);

    const float4* wl4 = reinterpret_cast<const float4*>(wlds);
    const float4* xrow = reinterpret_cast<const float4*>(X + (size_t)row * K);

    for (int k0 = 0; k0 < K; k0 += 4) {
        float4 xv = xrow[k0 >> 2];
        if (RELU) {
            xv.x = fmaxf(xv.x, 0.f); xv.y = fmaxf(xv.y, 0.f);
            xv.z = fmaxf(xv.z, 0.f); xv.w = fmaxf(xv.w, 0.f);
        }
#pragma unroll
        for (int kk = 0; kk < 4; kk++) {
            float xs = (kk == 0) ? xv.x : (kk == 1) ? xv.y : (kk == 2) ? xv.z : xv.w;
#pragma unroll
            for (int j = 0; j < 24; j++) {
                float4 w = wl4[(k0 + kk) * 24 + j];
                acc[j].x += xs * w.x;
                acc[j].y += xs * w.y;
                acc[j].z += xs * w.z;
                acc[j].w += xs * w.w;
            }
        }
    }

    float4* y4 = reinterpret_cast<float4*>(Y + (size_t)row * HIDDEN);
#pragma unroll
    for (int j = 0; j < 24; j++) y4[j] = acc[j];
}

// out[i][:] = dinv[i]^2 * xw[i][:] + b[:]   (self-loop contribution + bias)
__global__ __launch_bounds__(256) void init_out_kernel(const float* __restrict__ xw,
                                                       const float* __restrict__ dinv,
                                                       const float* __restrict__ b,
                                                       float* __restrict__ out, int n) {
    unsigned t = blockIdx.x * 256 + threadIdx.x;
    unsigned i = t / 24u, q = t % 24u;
    if (i >= (unsigned)n) return;
    float dv = dinv[i];
    float s = dv * dv;
    float4 v = reinterpret_cast<const float4*>(xw)[i * 24u + q];
    float4 bb = reinterpret_cast<const float4*>(b)[q];
    float4 o = make_float4(fmaf(s, v.x, bb.x), fmaf(s, v.y, bb.y),
                           fmaf(s, v.z, bb.z), fmaf(s, v.w, bb.w));
    reinterpret_cast<float4*>(out)[i * 24u + q] = o;
}

// out[dst[e]][:] += norm[e] * xw[src[e]][:]  — 24 threads/edge, float4 gather.
__global__ __launch_bounds__(256) void scatter_kernel(const float* __restrict__ xw,
                                                      const int* __restrict__ src,
                                                      const int* __restrict__ dst,
                                                      const float* __restrict__ nrm,
                                                      float* __restrict__ out, int E) {
    unsigned t = blockIdx.x * 256 + threadIdx.x;
    unsigned e = t / 24u, q = t % 24u;
    if (e >= (unsigned)E) return;
    int s = src[e];
    int d = dst[e];
    float nm = nrm[e];
    float4 v = reinterpret_cast<const float4*>(xw)[(unsigned)s * 24u + q];
    float* o = out + (size_t)d * HIDDEN + q * 4u;
    atomicAdd(o + 0, nm * v.x);
    atomicAdd(o + 1, nm * v.y);
    atomicAdd(o + 2, nm * v.z);
    atomicAdd(o + 3, nm * v.w);
}

// g[batch[i]][:] += relu(h[i][:])
__global__ __launch_bounds__(256) void pool_kernel(const float* __restrict__ h,
                                                   const int* __restrict__ batch,
                                                   float* __restrict__ g, int n) {
    unsigned t = blockIdx.x * 256 + threadIdx.x;
    unsigned i = t / 24u, q = t % 24u;
    if (i >= (unsigned)n) return;
    int b = batch[i];
    float4 v = reinterpret_cast<const float4*>(h)[i * 24u + q];
    float* o = g + (size_t)b * HIDDEN + q * 4u;
    atomicAdd(o + 0, fmaxf(v.x, 0.f));
    atomicAdd(o + 1, fmaxf(v.y, 0.f));
    atomicAdd(o + 2, fmaxf(v.z, 0.f));
    atomicAdd(o + 3, fmaxf(v.w, 0.f));
}

// out[g] = relu(g_row @ Wf1 + bf1) @ Wf2 + bf2  — one block per graph.
__global__ __launch_bounds__(64) void mlp_kernel(const float* __restrict__ g,
                                                 const float* __restrict__ Wf1,
                                                 const float* __restrict__ bf1,
                                                 const float* __restrict__ Wf2,
                                                 const float* __restrict__ bf2,
                                                 float* __restrict__ out, int G) {
    __shared__ float gs[HIDDEN];
    __shared__ float hid[32];
    int blk = blockIdx.x;
    int lane = threadIdx.x;
    for (int idx = lane; idx < HIDDEN; idx += 64) gs[idx] = g[(size_t)blk * HIDDEN + idx];
    __syncthreads();
    if (lane < 32) {
        float a = bf1[lane];
        for (int k = 0; k < HIDDEN; k++) a = fmaf(gs[k], Wf1[k * 32 + lane], a);
        hid[lane] = fmaxf(a, 0.f);
    }
    __syncthreads();
    if (lane == 0) {
        float o = bf2[0];
        for (int k = 0; k < 32; k++) o = fmaf(hid[k], Wf2[k], o);
        out[blk] = o;
    }
}

extern "C" void kernel_launch(void* const* d_in, const int* in_sizes, int n_in,
                              void* d_out, int out_size, void* d_ws, size_t ws_size,
                              hipStream_t stream) {
    const float* x     = (const float*)d_in[0];
    const int*   ei    = (const int*)d_in[1];
    const int*   batch = (const int*)d_in[2];
    const float* W1 = (const float*)d_in[3];  const float* b1 = (const float*)d_in[4];
    const float* W2 = (const float*)d_in[5];  const float* b2 = (const float*)d_in[6];
    const float* W3 = (const float*)d_in[7];  const float* b3 = (const float*)d_in[8];
    const float* W4 = (const float*)d_in[9];  const float* b4 = (const float*)d_in[10];
    const float* Wf1 = (const float*)d_in[11]; const float* bf1 = (const float*)d_in[12];
    const float* Wf2 = (const float*)d_in[13]; const float* bf2 = (const float*)d_in[14];
    float* out = (float*)d_out;

    int N = in_sizes[0] / 32;   // 100000
    int E = in_sizes[1] / 2;    // 1600000
    int G = out_size;           // 2048
    const int* src = ei;
    const int* dst = ei + E;

    // Workspace layout (all 256B aligned): ~84.4 MB total
    char* ws = (char*)d_ws;
    size_t off = 0;
    auto alloc = [&](size_t bytes) -> float* {
        float* p = (float*)(ws + off);
        off += (bytes + 255) & ~(size_t)255;
        return p;
    };
    float* deg  = alloc((size_t)N * 4);            // becomes dinv in place
    float* nrm  = alloc((size_t)E * 4);
    float* bufA = alloc((size_t)N * HIDDEN * 4);   // xw of current layer
    float* bufB = alloc((size_t)N * HIDDEN * 4);   // h of current layer
    float* gbuf = alloc((size_t)G * HIDDEN * 4);
    (void)ws_size;

    int gN   = (N + 255) / 256;
    int gE   = (E + 255) / 256;
    int gN24 = (int)(((long long)N * 24 + 255) / 256);
    int gE24 = (int)(((long long)E * 24 + 255) / 256);

    // ---- normalization precompute ----
    fill_ones<<<gN, 256, 0, stream>>>(deg, N);
    deg_count<<<gE, 256, 0, stream>>>(dst, deg, E);
    rsqrt_kernel<<<gN, 256, 0, stream>>>(deg, N);          // deg -> dinv
    norm_kernel<<<gE, 256, 0, stream>>>(src, dst, deg, nrm, E);

    // ---- layer 1 (K=32, input not relu'd) ----
    gemm_kernel<32, false><<<gN, 256, 0, stream>>>(x, W1, bufA, N);
    init_out_kernel<<<gN24, 256, 0, stream>>>(bufA, deg, b1, bufB, N);
    scatter_kernel<<<gE24, 256, 0, stream>>>(bufA, src, dst, nrm, bufB, E);

    // ---- layer 2 ----
    gemm_kernel<96, true><<<gN, 256, 0, stream>>>(bufB, W2, bufA, N);
    init_out_kernel<<<gN24, 256, 0, stream>>>(bufA, deg, b2, bufB, N);
    scatter_kernel<<<gE24, 256, 0, stream>>>(bufA, src, dst, nrm, bufB, E);

    // ---- layer 3 ----
    gemm_kernel<96, true><<<gN, 256, 0, stream>>>(bufB, W3, bufA, N);
    init_out_kernel<<<gN24, 256, 0, stream>>>(bufA, deg, b3, bufB, N);
    scatter_kernel<<<gE24, 256, 0, stream>>>(bufA, src, dst, nrm, bufB, E);

    // ---- layer 4 ----
    gemm_kernel<96, true><<<gN, 256, 0, stream>>>(bufB, W4, bufA, N);
    init_out_kernel<<<gN24, 256, 0, stream>>>(bufA, deg, b4, bufB, N);
    scatter_kernel<<<gE24, 256, 0, stream>>>(bufA, src, dst, nrm, bufB, E);

    // ---- pool + MLP head ----
    zero_kernel<<<(G * HIDDEN + 255) / 256, 256, 0, stream>>>(gbuf, G * HIDDEN);
    pool_kernel<<<gN24, 256, 0, stream>>>(bufB, batch, gbuf, N);
    mlp_kernel<<<G, 64, 0, stream>>>(gbuf, Wf1, bf1, Wf2, bf2, out, G);
}

// Round 2
// 1128.655 us; speedup vs baseline: 7.5501x; 7.5501x over previous
//
#include <hip/hip_runtime.h>

// GCN: 4x GCNConv(relu) -> global_add_pool -> MLP(96->32 relu ->1)
// N=100000 nodes, E=1600000 edges, F=32, H=96, G=2048 graphs. All fp32.
//
// R2: replace per-edge atomic scatter (atomic-throughput-bound, 2 ms/layer,
// 2.4 GB write amplification) with a CSR-by-dst gather built once per call.
// Aggregation = register accumulate + single write; self-loop+bias fused in.

#define HIDDEN 96

__global__ __launch_bounds__(256) void zero_int_kernel(int* p, int n) {
    int i = blockIdx.x * 256 + threadIdx.x;
    if (i < n) p[i] = 0;
}

__global__ __launch_bounds__(256) void zero_kernel(float* p, int n) {
    int i = blockIdx.x * 256 + threadIdx.x;
    if (i < n) p[i] = 0.0f;
}

// in-degree histogram over dst
__global__ __launch_bounds__(256) void deg_count_kernel(const int* __restrict__ dst,
                                                        int* __restrict__ cnt, int E) {
    int e = blockIdx.x * 256 + threadIdx.x;
    if (e < E) atomicAdd(&cnt[dst[e]], 1);
}

// dinv[i] = rsqrt(1 + in_degree)   (self-loop included)
__global__ __launch_bounds__(256) void dinv_kernel(const int* __restrict__ cnt,
                                                   float* __restrict__ dinv, int n) {
    int i = blockIdx.x * 256 + threadIdx.x;
    if (i < n) dinv[i] = rsqrtf((float)(cnt[i] + 1));
}

// Single-block chunked Hillis-Steele exclusive scan: rowptr[0..N], rowptr[N]=E.
// 98 chunks of 1024 — ~tens of µs, runs once per call.
__global__ __launch_bounds__(1024) void scan_kernel(const int* __restrict__ cnt,
                                                    int* __restrict__ rowptr, int N) {
    __shared__ int tmp[1024];
    __shared__ int carry_s;
    int tid = threadIdx.x;
    if (tid == 0) carry_s = 0;
    __syncthreads();
    for (int base = 0; base < N; base += 1024) {
        int i = base + tid;
        int v = (i < N) ? cnt[i] : 0;
        tmp[tid] = v;
        __syncthreads();
        for (int off = 1; off < 1024; off <<= 1) {
            int t = (tid >= off) ? tmp[tid - off] : 0;
            __syncthreads();
            tmp[tid] += t;
            __syncthreads();
        }
        if (i < N) rowptr[i] = carry_s + tmp[tid] - v;  // exclusive
        __syncthreads();
        if (tid == 0) carry_s += tmp[1023];
        __syncthreads();
    }
    if (tid == 0) rowptr[N] = carry_s;
}

// Fill CSR slots: col[slot]=src, val[slot]=dinv[src]*dinv[dst]. Order within a
// row is arbitrary (atomic cursor) — sum order only, well under threshold.
__global__ __launch_bounds__(256) void fill_csr_kernel(const int* __restrict__ src,
                                                       const int* __restrict__ dst,
                                                       const float* __restrict__ dinv,
                                                       const int* __restrict__ rowptr,
                                                       int* __restrict__ cursor,
                                                       int* __restrict__ col,
                                                       float* __restrict__ val, int E) {
    int e = blockIdx.x * 256 + threadIdx.x;
    if (e >= E) return;
    int s = src[e];
    int d = dst[e];
    int pos = atomicAdd(&cursor[d], 1);
    int idx = rowptr[d] + pos;
    col[idx] = s;
    val[idx] = dinv[s] * dinv[d];
}

// Y[n x 96] = act(X[n x K]) @ W[K x 96].  W in LDS (broadcast reads), one row
// per thread, 24 float4 accumulators.
template <int K, bool RELU>
__global__ __launch_bounds__(256) void gemm_kernel(const float* __restrict__ X,
                                                   const float* __restrict__ W,
                                                   float* __restrict__ Y, int n) {
    __shared__ float wlds[K * HIDDEN];
    for (int idx = threadIdx.x; idx < K * HIDDEN; idx += 256) wlds[idx] = W[idx];
    __syncthreads();

    int row = blockIdx.x * 256 + threadIdx.x;
    if (row >= n) return;

    float4 acc[24];
#pragma unroll
    for (int j = 0; j < 24; j++) acc[j] = make_float4(0.f, 0.f, 0.f, 0.f);

    const float4* wl4 = reinterpret_cast<const float4*>(wlds);
    const float4* xrow = reinterpret_cast<const float4*>(X + (size_t)row * K);

    for (int k0 = 0; k0 < K; k0 += 4) {
        float4 xv = xrow[k0 >> 2];
        if (RELU) {
            xv.x = fmaxf(xv.x, 0.f); xv.y = fmaxf(xv.y, 0.f);
            xv.z = fmaxf(xv.z, 0.f); xv.w = fmaxf(xv.w, 0.f);
        }
#pragma unroll
        for (int kk = 0; kk < 4; kk++) {
            float xs = (kk == 0) ? xv.x : (kk == 1) ? xv.y : (kk == 2) ? xv.z : xv.w;
#pragma unroll
            for (int j = 0; j < 24; j++) {
                float4 w = wl4[(k0 + kk) * 24 + j];
                acc[j].x += xs * w.x;
                acc[j].y += xs * w.y;
                acc[j].z += xs * w.z;
                acc[j].w += xs * w.w;
            }
        }
    }

    float4* y4 = reinterpret_cast<float4*>(Y + (size_t)row * HIDDEN);
#pragma unroll
    for (int j = 0; j < 24; j++) y4[j] = acc[j];
}

// out[i] = dinv[i]^2*xw[i] + b + sum_{e in in(i)} val[e]*xw[col[e]]
// 24 threads per node (one float4 lane each). No atomics. 2-way edge unroll
// for 2 outstanding gathers/thread; xw (38.4 MB) is L3-resident.
__global__ __launch_bounds__(256) void aggregate_kernel(const float* __restrict__ xw,
                                                        const int* __restrict__ rowptr,
                                                        const int* __restrict__ col,
                                                        const float* __restrict__ val,
                                                        const float* __restrict__ dinv,
                                                        const float* __restrict__ b,
                                                        float* __restrict__ out, int n) {
    unsigned t = blockIdx.x * 256 + threadIdx.x;
    unsigned i = t / 24u, q = t % 24u;
    if (i >= (unsigned)n) return;

    const float4* xw4 = reinterpret_cast<const float4*>(xw);
    float dv = dinv[i];
    float s = dv * dv;
    float4 self = xw4[i * 24u + q];
    float4 bb = reinterpret_cast<const float4*>(b)[q];
    float4 acc = make_float4(fmaf(s, self.x, bb.x), fmaf(s, self.y, bb.y),
                             fmaf(s, self.z, bb.z), fmaf(s, self.w, bb.w));

    int e = rowptr[i], end = rowptr[i + 1];
    for (; e + 1 < end; e += 2) {
        int c0 = col[e], c1 = col[e + 1];
        float w0 = val[e], w1 = val[e + 1];
        float4 v0 = xw4[(unsigned)c0 * 24u + q];
        float4 v1 = xw4[(unsigned)c1 * 24u + q];
        acc.x += w0 * v0.x + w1 * v1.x;
        acc.y += w0 * v0.y + w1 * v1.y;
        acc.z += w0 * v0.z + w1 * v1.z;
        acc.w += w0 * v0.w + w1 * v1.w;
    }
    if (e < end) {
        int c0 = col[e];
        float w0 = val[e];
        float4 v0 = xw4[(unsigned)c0 * 24u + q];
        acc.x += w0 * v0.x; acc.y += w0 * v0.y;
        acc.z += w0 * v0.z; acc.w += w0 * v0.w;
    }
    reinterpret_cast<float4*>(out)[i * 24u + q] = acc;
}

// g[batch[i]] += relu(h[i])  — G*96 = 786 KB, L2-resident, atomics fine.
__global__ __launch_bounds__(256) void pool_kernel(const float* __restrict__ h,
                                                   const int* __restrict__ batch,
                                                   float* __restrict__ g, int n) {
    unsigned t = blockIdx.x * 256 + threadIdx.x;
    unsigned i = t / 24u, q = t % 24u;
    if (i >= (unsigned)n) return;
    int b = batch[i];
    float4 v = reinterpret_cast<const float4*>(h)[i * 24u + q];
    float* o = g + (size_t)b * HIDDEN + q * 4u;
    atomicAdd(o + 0, fmaxf(v.x, 0.f));
    atomicAdd(o + 1, fmaxf(v.y, 0.f));
    atomicAdd(o + 2, fmaxf(v.z, 0.f));
    atomicAdd(o + 3, fmaxf(v.w, 0.f));
}

__global__ __launch_bounds__(64) void mlp_kernel(const float* __restrict__ g,
                                                 const float* __restrict__ Wf1,
                                                 const float* __restrict__ bf1,
                                                 const float* __restrict__ Wf2,
                                                 const float* __restrict__ bf2,
                                                 float* __restrict__ out, int G) {
    __shared__ float gs[HIDDEN];
    __shared__ float hid[32];
    int blk = blockIdx.x;
    int lane = threadIdx.x;
    for (int idx = lane; idx < HIDDEN; idx += 64) gs[idx] = g[(size_t)blk * HIDDEN + idx];
    __syncthreads();
    if (lane < 32) {
        float a = bf1[lane];
        for (int k = 0; k < HIDDEN; k++) a = fmaf(gs[k], Wf1[k * 32 + lane], a);
        hid[lane] = fmaxf(a, 0.f);
    }
    __syncthreads();
    if (lane == 0) {
        float o = bf2[0];
        for (int k = 0; k < 32; k++) o = fmaf(hid[k], Wf2[k], o);
        out[blk] = o;
    }
}

extern "C" void kernel_launch(void* const* d_in, const int* in_sizes, int n_in,
                              void* d_out, int out_size, void* d_ws, size_t ws_size,
                              hipStream_t stream) {
    const float* x     = (const float*)d_in[0];
    const int*   ei    = (const int*)d_in[1];
    const int*   batch = (const int*)d_in[2];
    const float* W1 = (const float*)d_in[3];  const float* b1 = (const float*)d_in[4];
    const float* W2 = (const float*)d_in[5];  const float* b2 = (const float*)d_in[6];
    const float* W3 = (const float*)d_in[7];  const float* b3 = (const float*)d_in[8];
    const float* W4 = (const float*)d_in[9];  const float* b4 = (const float*)d_in[10];
    const float* Wf1 = (const float*)d_in[11]; const float* bf1 = (const float*)d_in[12];
    const float* Wf2 = (const float*)d_in[13]; const float* bf2 = (const float*)d_in[14];
    float* out = (float*)d_out;

    int N = in_sizes[0] / 32;   // 100000
    int E = in_sizes[1] / 2;    // 1600000
    int G = out_size;           // 2048
    const int* src = ei;
    const int* dst = ei + E;

    // Workspace layout (~92 MB)
    char* ws = (char*)d_ws;
    size_t off = 0;
    auto alloc = [&](size_t bytes) -> void* {
        void* p = (void*)(ws + off);
        off += (bytes + 255) & ~(size_t)255;
        return p;
    };
    int*   degcnt = (int*)alloc((size_t)N * 4);
    int*   cursor = (int*)alloc((size_t)N * 4);
    float* dinv   = (float*)alloc((size_t)N * 4);
    int*   rowptr = (int*)alloc((size_t)(N + 1) * 4);
    int*   col    = (int*)alloc((size_t)E * 4);
    float* val    = (float*)alloc((size_t)E * 4);
    float* bufA   = (float*)alloc((size_t)N * HIDDEN * 4);
    float* bufB   = (float*)alloc((size_t)N * HIDDEN * 4);
    float* gbuf   = (float*)alloc((size_t)G * HIDDEN * 4);
    (void)ws_size;

    int gN   = (N + 255) / 256;
    int gE   = (E + 255) / 256;
    int gN24 = (int)(((long long)N * 24 + 255) / 256);

    // ---- CSR build (once per call) ----
    zero_int_kernel<<<gN, 256, 0, stream>>>(degcnt, N);
    zero_int_kernel<<<gN, 256, 0, stream>>>(cursor, N);
    deg_count_kernel<<<gE, 256, 0, stream>>>(dst, degcnt, E);
    dinv_kernel<<<gN, 256, 0, stream>>>(degcnt, dinv, N);
    scan_kernel<<<1, 1024, 0, stream>>>(degcnt, rowptr, N);
    fill_csr_kernel<<<gE, 256, 0, stream>>>(src, dst, dinv, rowptr, cursor, col, val, E);

    // ---- layer 1 (K=32, input not relu'd) ----
    gemm_kernel<32, false><<<gN, 256, 0, stream>>>(x, W1, bufA, N);
    aggregate_kernel<<<gN24, 256, 0, stream>>>(bufA, rowptr, col, val, dinv, b1, bufB, N);

    // ---- layers 2-4 ----
    gemm_kernel<96, true><<<gN, 256, 0, stream>>>(bufB, W2, bufA, N);
    aggregate_kernel<<<gN24, 256, 0, stream>>>(bufA, rowptr, col, val, dinv, b2, bufB, N);

    gemm_kernel<96, true><<<gN, 256, 0, stream>>>(bufB, W3, bufA, N);
    aggregate_kernel<<<gN24, 256, 0, stream>>>(bufA, rowptr, col, val, dinv, b3, bufB, N);

    gemm_kernel<96, true><<<gN, 256, 0, stream>>>(bufB, W4, bufA, N);
    aggregate_kernel<<<gN24, 256, 0, stream>>>(bufA, rowptr, col, val, dinv, b4, bufB, N);

    // ---- pool + MLP head ----
    zero_kernel<<<(G * HIDDEN + 255) / 256, 256, 0, stream>>>(gbuf, G * HIDDEN);
    pool_kernel<<<gN24, 256, 0, stream>>>(bufB, batch, gbuf, N);
    mlp_kernel<<<G, 64, 0, stream>>>(gbuf, Wf1, bf1, Wf2, bf2, out, G);
}

// Round 3
// 856.673 us; speedup vs baseline: 9.9472x; 1.3175x over previous
//
#include <hip/hip_runtime.h>

// GCN: 4x GCNConv(relu) -> global_add_pool -> MLP(96->32 relu ->1)
// N=100000 nodes, E=1600000 edges, F=32, H=96, G=2048 graphs. All fp32.
//
// R3: multi-block scan (was single-block, 176 us @ 0.18% occupancy),
// slot positions captured in deg_count (kills fill_csr atomic pass),
// pool fused into layer-4 aggregate (kills one 38MB write + 38MB read).

#define HIDDEN 96

__global__ __launch_bounds__(256) void zero_int_kernel(int* p, int n) {
    int i = blockIdx.x * 256 + threadIdx.x;
    if (i < n) p[i] = 0;
}

__global__ __launch_bounds__(256) void zero_kernel(float* p, int n) {
    int i = blockIdx.x * 256 + threadIdx.x;
    if (i < n) p[i] = 0.0f;
}

// in-degree histogram over dst; epos[e] = this edge's slot within its dst row
__global__ __launch_bounds__(256) void deg_pos_kernel(const int* __restrict__ dst,
                                                      int* __restrict__ cnt,
                                                      int* __restrict__ epos, int E) {
    int e = blockIdx.x * 256 + threadIdx.x;
    if (e < E) epos[e] = atomicAdd(&cnt[dst[e]], 1);
}

// dinv[i] = rsqrt(1 + in_degree)   (self-loop included)
__global__ __launch_bounds__(256) void dinv_kernel(const int* __restrict__ cnt,
                                                   float* __restrict__ dinv, int n) {
    int i = blockIdx.x * 256 + threadIdx.x;
    if (i < n) dinv[i] = rsqrtf((float)(cnt[i] + 1));
}

// ---- 3-phase multi-block exclusive scan of cnt[0..N) -> rowptr ----
// phase 1: block b sums its 1024-element chunk into bsum[b]
__global__ __launch_bounds__(256) void scan_reduce_kernel(const int* __restrict__ cnt,
                                                          int* __restrict__ bsum, int N) {
    __shared__ int s[256];
    int b = blockIdx.x, tid = threadIdx.x;
    int base = b * 1024;
    int v = 0;
    for (int j = tid; j < 1024; j += 256) {
        int i = base + j;
        v += (i < N) ? cnt[i] : 0;
    }
    s[tid] = v;
    __syncthreads();
    for (int off = 128; off > 0; off >>= 1) {
        if (tid < off) s[tid] += s[tid + off];
        __syncthreads();
    }
    if (tid == 0) bsum[b] = s[0];
}

// phase 2: exclusive scan of bsum[0..nb) in one small block (nb <= 128)
__global__ __launch_bounds__(128) void scan_bsum_kernel(int* __restrict__ bsum, int nb) {
    __shared__ int s[128];
    int tid = threadIdx.x;
    int v = (tid < nb) ? bsum[tid] : 0;
    s[tid] = v;
    __syncthreads();
    for (int off = 1; off < 128; off <<= 1) {
        int t = (tid >= off) ? s[tid - off] : 0;
        __syncthreads();
        s[tid] += t;
        __syncthreads();
    }
    if (tid < nb) bsum[tid] = s[tid] - v;  // exclusive
}

// phase 3: block b writes exclusive scan of its chunk, offset by bsum[b]
__global__ __launch_bounds__(256) void scan_write_kernel(const int* __restrict__ cnt,
                                                         const int* __restrict__ bsum,
                                                         int* __restrict__ rowptr,
                                                         int N, int E) {
    __shared__ int ts[256];
    int b = blockIdx.x, tid = threadIdx.x;
    int base = b * 1024 + tid * 4;
    int v0 = (base + 0 < N) ? cnt[base + 0] : 0;
    int v1 = (base + 1 < N) ? cnt[base + 1] : 0;
    int v2 = (base + 2 < N) ? cnt[base + 2] : 0;
    int v3 = (base + 3 < N) ? cnt[base + 3] : 0;
    int sum = v0 + v1 + v2 + v3;
    ts[tid] = sum;
    __syncthreads();
    for (int off = 1; off < 256; off <<= 1) {
        int t = (tid >= off) ? ts[tid - off] : 0;
        __syncthreads();
        ts[tid] += t;
        __syncthreads();
    }
    int excl = bsum[b] + ts[tid] - sum;
    if (base + 0 < N) rowptr[base + 0] = excl;
    if (base + 1 < N) rowptr[base + 1] = excl + v0;
    if (base + 2 < N) rowptr[base + 2] = excl + v0 + v1;
    if (base + 3 < N) rowptr[base + 3] = excl + v0 + v1 + v2;
    if (b == 0 && tid == 0) rowptr[N] = E;
}

// Fill CSR slots (no atomics: slot position precomputed in epos).
__global__ __launch_bounds__(256) void fill_csr_kernel(const int* __restrict__ src,
                                                       const int* __restrict__ dst,
                                                       const int* __restrict__ epos,
                                                       const float* __restrict__ dinv,
                                                       const int* __restrict__ rowptr,
                                                       int* __restrict__ col,
                                                       float* __restrict__ val, int E) {
    int e = blockIdx.x * 256 + threadIdx.x;
    if (e >= E) return;
    int s = src[e];
    int d = dst[e];
    int idx = rowptr[d] + epos[e];
    col[idx] = s;
    val[idx] = dinv[s] * dinv[d];
}

// Y[n x 96] = act(X[n x K]) @ W[K x 96].  W in LDS (broadcast reads), one row
// per thread, 24 float4 accumulators.
template <int K, bool RELU>
__global__ __launch_bounds__(256) void gemm_kernel(const float* __restrict__ X,
                                                   const float* __restrict__ W,
                                                   float* __restrict__ Y, int n) {
    __shared__ float wlds[K * HIDDEN];
    for (int idx = threadIdx.x; idx < K * HIDDEN; idx += 256) wlds[idx] = W[idx];
    __syncthreads();

    int row = blockIdx.x * 256 + threadIdx.x;
    if (row >= n) return;

    float4 acc[24];
#pragma unroll
    for (int j = 0; j < 24; j++) acc[j] = make_float4(0.f, 0.f, 0.f, 0.f);

    const float4* wl4 = reinterpret_cast<const float4*>(wlds);
    const float4* xrow = reinterpret_cast<const float4*>(X + (size_t)row * K);

    for (int k0 = 0; k0 < K; k0 += 4) {
        float4 xv = xrow[k0 >> 2];
        if (RELU) {
            xv.x = fmaxf(xv.x, 0.f); xv.y = fmaxf(xv.y, 0.f);
            xv.z = fmaxf(xv.z, 0.f); xv.w = fmaxf(xv.w, 0.f);
        }
#pragma unroll
        for (int kk = 0; kk < 4; kk++) {
            float xs = (kk == 0) ? xv.x : (kk == 1) ? xv.y : (kk == 2) ? xv.z : xv.w;
#pragma unroll
            for (int j = 0; j < 24; j++) {
                float4 w = wl4[(k0 + kk) * 24 + j];
                acc[j].x += xs * w.x;
                acc[j].y += xs * w.y;
                acc[j].z += xs * w.z;
                acc[j].w += xs * w.w;
            }
        }
    }

    float4* y4 = reinterpret_cast<float4*>(Y + (size_t)row * HIDDEN);
#pragma unroll
    for (int j = 0; j < 24; j++) y4[j] = acc[j];
}

// out[i] = dinv[i]^2*xw[i] + b + sum_{e in in(i)} val[e]*xw[col[e]]
// 24 threads per node (one float4 lane each). 4-way edge unroll for MLP.
// POOL=true (last layer): skip writing out; atomicAdd relu(acc) into
// gpool[batch[i]] instead (saves a 38MB write + 38MB read pass).
template <bool POOL>
__global__ __launch_bounds__(256) void aggregate_kernel(const float* __restrict__ xw,
                                                        const int* __restrict__ rowptr,
                                                        const int* __restrict__ col,
                                                        const float* __restrict__ val,
                                                        const float* __restrict__ dinv,
                                                        const float* __restrict__ b,
                                                        float* __restrict__ out,
                                                        const int* __restrict__ batch,
                                                        float* __restrict__ gpool, int n) {
    unsigned t = blockIdx.x * 256 + threadIdx.x;
    unsigned i = t / 24u, q = t % 24u;
    if (i >= (unsigned)n) return;

    const float4* xw4 = reinterpret_cast<const float4*>(xw);
    float dv = dinv[i];
    float s = dv * dv;
    float4 self = xw4[i * 24u + q];
    float4 bb = reinterpret_cast<const float4*>(b)[q];
    float4 acc = make_float4(fmaf(s, self.x, bb.x), fmaf(s, self.y, bb.y),
                             fmaf(s, self.z, bb.z), fmaf(s, self.w, bb.w));

    int e = rowptr[i], end = rowptr[i + 1];
    for (; e + 3 < end; e += 4) {
        int c0 = col[e], c1 = col[e + 1], c2 = col[e + 2], c3 = col[e + 3];
        float w0 = val[e], w1 = val[e + 1], w2 = val[e + 2], w3 = val[e + 3];
        float4 v0 = xw4[(unsigned)c0 * 24u + q];
        float4 v1 = xw4[(unsigned)c1 * 24u + q];
        float4 v2 = xw4[(unsigned)c2 * 24u + q];
        float4 v3 = xw4[(unsigned)c3 * 24u + q];
        acc.x += w0 * v0.x + w1 * v1.x + w2 * v2.x + w3 * v3.x;
        acc.y += w0 * v0.y + w1 * v1.y + w2 * v2.y + w3 * v3.y;
        acc.z += w0 * v0.z + w1 * v1.z + w2 * v2.z + w3 * v3.z;
        acc.w += w0 * v0.w + w1 * v1.w + w2 * v2.w + w3 * v3.w;
    }
    for (; e < end; e++) {
        int c0 = col[e];
        float w0 = val[e];
        float4 v0 = xw4[(unsigned)c0 * 24u + q];
        acc.x += w0 * v0.x; acc.y += w0 * v0.y;
        acc.z += w0 * v0.z; acc.w += w0 * v0.w;
    }

    if (POOL) {
        float* o = gpool + (size_t)batch[i] * HIDDEN + q * 4u;
        atomicAdd(o + 0, fmaxf(acc.x, 0.f));
        atomicAdd(o + 1, fmaxf(acc.y, 0.f));
        atomicAdd(o + 2, fmaxf(acc.z, 0.f));
        atomicAdd(o + 3, fmaxf(acc.w, 0.f));
    } else {
        reinterpret_cast<float4*>(out)[i * 24u + q] = acc;
    }
}

__global__ __launch_bounds__(64) void mlp_kernel(const float* __restrict__ g,
                                                 const float* __restrict__ Wf1,
                                                 const float* __restrict__ bf1,
                                                 const float* __restrict__ Wf2,
                                                 const float* __restrict__ bf2,
                                                 float* __restrict__ out, int G) {
    __shared__ float gs[HIDDEN];
    __shared__ float hid[32];
    int blk = blockIdx.x;
    int lane = threadIdx.x;
    for (int idx = lane; idx < HIDDEN; idx += 64) gs[idx] = g[(size_t)blk * HIDDEN + idx];
    __syncthreads();
    if (lane < 32) {
        float a = bf1[lane];
        for (int k = 0; k < HIDDEN; k++) a = fmaf(gs[k], Wf1[k * 32 + lane], a);
        hid[lane] = fmaxf(a, 0.f);
    }
    __syncthreads();
    if (lane == 0) {
        float o = bf2[0];
        for (int k = 0; k < 32; k++) o = fmaf(hid[k], Wf2[k], o);
        out[blk] = o;
    }
}

extern "C" void kernel_launch(void* const* d_in, const int* in_sizes, int n_in,
                              void* d_out, int out_size, void* d_ws, size_t ws_size,
                              hipStream_t stream) {
    const float* x     = (const float*)d_in[0];
    const int*   ei    = (const int*)d_in[1];
    const int*   batch = (const int*)d_in[2];
    const float* W1 = (const float*)d_in[3];  const float* b1 = (const float*)d_in[4];
    const float* W2 = (const float*)d_in[5];  const float* b2 = (const float*)d_in[6];
    const float* W3 = (const float*)d_in[7];  const float* b3 = (const float*)d_in[8];
    const float* W4 = (const float*)d_in[9];  const float* b4 = (const float*)d_in[10];
    const float* Wf1 = (const float*)d_in[11]; const float* bf1 = (const float*)d_in[12];
    const float* Wf2 = (const float*)d_in[13]; const float* bf2 = (const float*)d_in[14];
    float* out = (float*)d_out;

    int N = in_sizes[0] / 32;   // 100000
    int E = in_sizes[1] / 2;    // 1600000
    int G = out_size;           // 2048
    const int* src = ei;
    const int* dst = ei + E;

    // Workspace layout (~92 MB)
    char* ws = (char*)d_ws;
    size_t off = 0;
    auto alloc = [&](size_t bytes) -> void* {
        void* p = (void*)(ws + off);
        off += (bytes + 255) & ~(size_t)255;
        return p;
    };
    int*   degcnt = (int*)alloc((size_t)N * 4);
    float* dinv   = (float*)alloc((size_t)N * 4);
    int*   rowptr = (int*)alloc((size_t)(N + 1) * 4);
    int*   bsum   = (int*)alloc((size_t)128 * 4);
    int*   col    = (int*)alloc((size_t)E * 4);
    float* val    = (float*)alloc((size_t)E * 4);
    float* bufA   = (float*)alloc((size_t)N * HIDDEN * 4);
    float* bufB   = (float*)alloc((size_t)N * HIDDEN * 4);
    float* gbuf   = (float*)alloc((size_t)G * HIDDEN * 4);
    (void)ws_size;

    // epos (E ints) aliases bufA: dead once fill_csr completes, before gemm-1.
    int* epos = (int*)bufA;

    int gN   = (N + 255) / 256;
    int gE   = (E + 255) / 256;
    int gN24 = (int)(((long long)N * 24 + 255) / 256);
    int nb   = (N + 1023) / 1024;   // 98 scan blocks (<= 128)

    // ---- CSR build (once per call) ----
    zero_int_kernel<<<gN, 256, 0, stream>>>(degcnt, N);
    deg_pos_kernel<<<gE, 256, 0, stream>>>(dst, degcnt, epos, E);
    dinv_kernel<<<gN, 256, 0, stream>>>(degcnt, dinv, N);
    scan_reduce_kernel<<<nb, 256, 0, stream>>>(degcnt, bsum, N);
    scan_bsum_kernel<<<1, 128, 0, stream>>>(bsum, nb);
    scan_write_kernel<<<nb, 256, 0, stream>>>(degcnt, bsum, rowptr, N, E);
    fill_csr_kernel<<<gE, 256, 0, stream>>>(src, dst, epos, dinv, rowptr, col, val, E);

    // ---- layer 1 (K=32, input not relu'd) ----
    gemm_kernel<32, false><<<gN, 256, 0, stream>>>(x, W1, bufA, N);
    aggregate_kernel<false><<<gN24, 256, 0, stream>>>(bufA, rowptr, col, val, dinv, b1,
                                                      bufB, nullptr, nullptr, N);

    // ---- layers 2-3 ----
    gemm_kernel<96, true><<<gN, 256, 0, stream>>>(bufB, W2, bufA, N);
    aggregate_kernel<false><<<gN24, 256, 0, stream>>>(bufA, rowptr, col, val, dinv, b2,
                                                      bufB, nullptr, nullptr, N);

    gemm_kernel<96, true><<<gN, 256, 0, stream>>>(bufB, W3, bufA, N);
    aggregate_kernel<false><<<gN24, 256, 0, stream>>>(bufA, rowptr, col, val, dinv, b3,
                                                      bufB, nullptr, nullptr, N);

    // ---- layer 4: aggregate fused with relu + global_add_pool ----
    zero_kernel<<<(G * HIDDEN + 255) / 256, 256, 0, stream>>>(gbuf, G * HIDDEN);
    gemm_kernel<96, true><<<gN, 256, 0, stream>>>(bufB, W4, bufA, N);
    aggregate_kernel<true><<<gN24, 256, 0, stream>>>(bufA, rowptr, col, val, dinv, b4,
                                                     nullptr, batch, gbuf, N);

    // ---- MLP head ----
    mlp_kernel<<<G, 64, 0, stream>>>(gbuf, Wf1, bf1, Wf2, bf2, out, G);
}

// Round 4
// 851.837 us; speedup vs baseline: 10.0036x; 1.0057x over previous
//
#include <hip/hip_runtime.h>

// GCN: 4x GCNConv(relu) -> global_add_pool -> MLP(96->32 relu ->1)
// N=100000 nodes, E=1600000 edges, F=32, H=96, G=2048 graphs. All fp32.
//
// R4: (a) layer-1 reassociation: Â(X W1) = (Â X) W1 — aggregate 32-feat input
// first (3x less gather traffic), bias fused into GEMM. (b) aggregation ILP:
// 12 threads/node x 2 float4 x 4-way edge unroll = 8 outstanding gathers per
// thread (was 4), halves col/val broadcast loads.

#define HIDDEN 96

__global__ __launch_bounds__(256) void zero_int_kernel(int* p, int n) {
    int i = blockIdx.x * 256 + threadIdx.x;
    if (i < n) p[i] = 0;
}

__global__ __launch_bounds__(256) void zero_kernel(float* p, int n) {
    int i = blockIdx.x * 256 + threadIdx.x;
    if (i < n) p[i] = 0.0f;
}

// in-degree histogram over dst; epos[e] = this edge's slot within its dst row
__global__ __launch_bounds__(256) void deg_pos_kernel(const int* __restrict__ dst,
                                                      int* __restrict__ cnt,
                                                      int* __restrict__ epos, int E) {
    int e = blockIdx.x * 256 + threadIdx.x;
    if (e < E) epos[e] = atomicAdd(&cnt[dst[e]], 1);
}

__global__ __launch_bounds__(256) void dinv_kernel(const int* __restrict__ cnt,
                                                   float* __restrict__ dinv, int n) {
    int i = blockIdx.x * 256 + threadIdx.x;
    if (i < n) dinv[i] = rsqrtf((float)(cnt[i] + 1));
}

// ---- 3-phase multi-block exclusive scan of cnt[0..N) -> rowptr ----
__global__ __launch_bounds__(256) void scan_reduce_kernel(const int* __restrict__ cnt,
                                                          int* __restrict__ bsum, int N) {
    __shared__ int s[256];
    int b = blockIdx.x, tid = threadIdx.x;
    int base = b * 1024;
    int v = 0;
    for (int j = tid; j < 1024; j += 256) {
        int i = base + j;
        v += (i < N) ? cnt[i] : 0;
    }
    s[tid] = v;
    __syncthreads();
    for (int off = 128; off > 0; off >>= 1) {
        if (tid < off) s[tid] += s[tid + off];
        __syncthreads();
    }
    if (tid == 0) bsum[b] = s[0];
}

__global__ __launch_bounds__(128) void scan_bsum_kernel(int* __restrict__ bsum, int nb) {
    __shared__ int s[128];
    int tid = threadIdx.x;
    int v = (tid < nb) ? bsum[tid] : 0;
    s[tid] = v;
    __syncthreads();
    for (int off = 1; off < 128; off <<= 1) {
        int t = (tid >= off) ? s[tid - off] : 0;
        __syncthreads();
        s[tid] += t;
        __syncthreads();
    }
    if (tid < nb) bsum[tid] = s[tid] - v;  // exclusive
}

__global__ __launch_bounds__(256) void scan_write_kernel(const int* __restrict__ cnt,
                                                         const int* __restrict__ bsum,
                                                         int* __restrict__ rowptr,
                                                         int N, int E) {
    __shared__ int ts[256];
    int b = blockIdx.x, tid = threadIdx.x;
    int base = b * 1024 + tid * 4;
    int v0 = (base + 0 < N) ? cnt[base + 0] : 0;
    int v1 = (base + 1 < N) ? cnt[base + 1] : 0;
    int v2 = (base + 2 < N) ? cnt[base + 2] : 0;
    int v3 = (base + 3 < N) ? cnt[base + 3] : 0;
    int sum = v0 + v1 + v2 + v3;
    ts[tid] = sum;
    __syncthreads();
    for (int off = 1; off < 256; off <<= 1) {
        int t = (tid >= off) ? ts[tid - off] : 0;
        __syncthreads();
        ts[tid] += t;
        __syncthreads();
    }
    int excl = bsum[b] + ts[tid] - sum;
    if (base + 0 < N) rowptr[base + 0] = excl;
    if (base + 1 < N) rowptr[base + 1] = excl + v0;
    if (base + 2 < N) rowptr[base + 2] = excl + v0 + v1;
    if (base + 3 < N) rowptr[base + 3] = excl + v0 + v1 + v2;
    if (b == 0 && tid == 0) rowptr[N] = E;
}

// Fill CSR slots (no atomics: slot position precomputed in epos).
__global__ __launch_bounds__(256) void fill_csr_kernel(const int* __restrict__ src,
                                                       const int* __restrict__ dst,
                                                       const int* __restrict__ epos,
                                                       const float* __restrict__ dinv,
                                                       const int* __restrict__ rowptr,
                                                       int* __restrict__ col,
                                                       float* __restrict__ val, int E) {
    int e = blockIdx.x * 256 + threadIdx.x;
    if (e >= E) return;
    int s = src[e];
    int d = dst[e];
    int idx = rowptr[d] + epos[e];
    col[idx] = s;
    val[idx] = dinv[s] * dinv[d];
}

// Y[n x 96] = act(X[n x K]) @ W[K x 96] (+ b).  W in LDS (broadcast reads),
// one row per thread, 24 float4 accumulators.
template <int K, bool RELU, bool BIAS>
__global__ __launch_bounds__(256) void gemm_kernel(const float* __restrict__ X,
                                                   const float* __restrict__ W,
                                                   const float* __restrict__ b,
                                                   float* __restrict__ Y, int n) {
    __shared__ float wlds[K * HIDDEN];
    for (int idx = threadIdx.x; idx < K * HIDDEN; idx += 256) wlds[idx] = W[idx];
    __syncthreads();

    int row = blockIdx.x * 256 + threadIdx.x;
    if (row >= n) return;

    float4 acc[24];
#pragma unroll
    for (int j = 0; j < 24; j++) acc[j] = make_float4(0.f, 0.f, 0.f, 0.f);

    const float4* wl4 = reinterpret_cast<const float4*>(wlds);
    const float4* xrow = reinterpret_cast<const float4*>(X + (size_t)row * K);

    for (int k0 = 0; k0 < K; k0 += 4) {
        float4 xv = xrow[k0 >> 2];
        if (RELU) {
            xv.x = fmaxf(xv.x, 0.f); xv.y = fmaxf(xv.y, 0.f);
            xv.z = fmaxf(xv.z, 0.f); xv.w = fmaxf(xv.w, 0.f);
        }
#pragma unroll
        for (int kk = 0; kk < 4; kk++) {
            float xs = (kk == 0) ? xv.x : (kk == 1) ? xv.y : (kk == 2) ? xv.z : xv.w;
#pragma unroll
            for (int j = 0; j < 24; j++) {
                float4 w = wl4[(k0 + kk) * 24 + j];
                acc[j].x += xs * w.x;
                acc[j].y += xs * w.y;
                acc[j].z += xs * w.z;
                acc[j].w += xs * w.w;
            }
        }
    }

    float4* y4 = reinterpret_cast<float4*>(Y + (size_t)row * HIDDEN);
#pragma unroll
    for (int j = 0; j < 24; j++) {
        if (BIAS) {
            float4 bb = reinterpret_cast<const float4*>(b)[j];
            acc[j].x += bb.x; acc[j].y += bb.y; acc[j].z += bb.z; acc[j].w += bb.w;
        }
        y4[j] = acc[j];
    }
}

// out[i] = dinv[i]^2*xw[i] (+ b) + sum_{e in in(i)} val[e]*xw[col[e]]
// TPN threads/node, VPT float4s/thread (features TPN*VPT*4), 4-way edge
// unroll -> 4*VPT outstanding gathers per thread. Strided float4 layout
// (v*TPN+q) keeps each gather instruction coalesced within the node group.
// POOL: atomicAdd relu(acc) into gpool[batch[i]] instead of writing out.
template <int TPN, int VPT, bool POOL, bool BIAS>
__global__ __launch_bounds__(256) void aggregate_kernel(const float* __restrict__ xw,
                                                        const int* __restrict__ rowptr,
                                                        const int* __restrict__ col,
                                                        const float* __restrict__ val,
                                                        const float* __restrict__ dinv,
                                                        const float* __restrict__ b,
                                                        float* __restrict__ out,
                                                        const int* __restrict__ batch,
                                                        float* __restrict__ gpool, int n) {
    constexpr int F4 = TPN * VPT;   // float4s per node row
    unsigned t = blockIdx.x * 256 + threadIdx.x;
    unsigned i = t / (unsigned)TPN, q = t % (unsigned)TPN;
    if (i >= (unsigned)n) return;

    const float4* xw4 = reinterpret_cast<const float4*>(xw);
    float dv = dinv[i];
    float s = dv * dv;

    float4 acc[VPT];
#pragma unroll
    for (int v = 0; v < VPT; v++) {
        float4 self = xw4[i * F4 + v * TPN + q];
        float4 a = make_float4(s * self.x, s * self.y, s * self.z, s * self.w);
        if (BIAS) {
            float4 bb = reinterpret_cast<const float4*>(b)[v * TPN + q];
            a.x += bb.x; a.y += bb.y; a.z += bb.z; a.w += bb.w;
        }
        acc[v] = a;
    }

    int e = rowptr[i], end = rowptr[i + 1];
    for (; e + 3 < end; e += 4) {
        int c0 = col[e], c1 = col[e + 1], c2 = col[e + 2], c3 = col[e + 3];
        float w0 = val[e], w1 = val[e + 1], w2 = val[e + 2], w3 = val[e + 3];
        float4 g0[VPT], g1[VPT], g2[VPT], g3[VPT];
#pragma unroll
        for (int v = 0; v < VPT; v++) {
            unsigned o = v * TPN + q;
            g0[v] = xw4[(unsigned)c0 * F4 + o];
            g1[v] = xw4[(unsigned)c1 * F4 + o];
            g2[v] = xw4[(unsigned)c2 * F4 + o];
            g3[v] = xw4[(unsigned)c3 * F4 + o];
        }
#pragma unroll
        for (int v = 0; v < VPT; v++) {
            acc[v].x += w0 * g0[v].x + w1 * g1[v].x + w2 * g2[v].x + w3 * g3[v].x;
            acc[v].y += w0 * g0[v].y + w1 * g1[v].y + w2 * g2[v].y + w3 * g3[v].y;
            acc[v].z += w0 * g0[v].z + w1 * g1[v].z + w2 * g2[v].z + w3 * g3[v].z;
            acc[v].w += w0 * g0[v].w + w1 * g1[v].w + w2 * g2[v].w + w3 * g3[v].w;
        }
    }
    for (; e < end; e++) {
        int c0 = col[e];
        float w0 = val[e];
#pragma unroll
        for (int v = 0; v < VPT; v++) {
            float4 g = xw4[(unsigned)c0 * F4 + v * TPN + q];
            acc[v].x += w0 * g.x; acc[v].y += w0 * g.y;
            acc[v].z += w0 * g.z; acc[v].w += w0 * g.w;
        }
    }

    if (POOL) {
        float* o = gpool + (size_t)batch[i] * (F4 * 4);
#pragma unroll
        for (int v = 0; v < VPT; v++) {
            unsigned fo = (v * TPN + q) * 4u;
            atomicAdd(o + fo + 0, fmaxf(acc[v].x, 0.f));
            atomicAdd(o + fo + 1, fmaxf(acc[v].y, 0.f));
            atomicAdd(o + fo + 2, fmaxf(acc[v].z, 0.f));
            atomicAdd(o + fo + 3, fmaxf(acc[v].w, 0.f));
        }
    } else {
        float4* o4 = reinterpret_cast<float4*>(out);
#pragma unroll
        for (int v = 0; v < VPT; v++) o4[i * F4 + v * TPN + q] = acc[v];
    }
}

__global__ __launch_bounds__(64) void mlp_kernel(const float* __restrict__ g,
                                                 const float* __restrict__ Wf1,
                                                 const float* __restrict__ bf1,
                                                 const float* __restrict__ Wf2,
                                                 const float* __restrict__ bf2,
                                                 float* __restrict__ out, int G) {
    __shared__ float gs[HIDDEN];
    __shared__ float hid[32];
    int blk = blockIdx.x;
    int lane = threadIdx.x;
    for (int idx = lane; idx < HIDDEN; idx += 64) gs[idx] = g[(size_t)blk * HIDDEN + idx];
    __syncthreads();
    if (lane < 32) {
        float a = bf1[lane];
        for (int k = 0; k < HIDDEN; k++) a = fmaf(gs[k], Wf1[k * 32 + lane], a);
        hid[lane] = fmaxf(a, 0.f);
    }
    __syncthreads();
    if (lane == 0) {
        float o = bf2[0];
        for (int k = 0; k < 32; k++) o = fmaf(hid[k], Wf2[k], o);
        out[blk] = o;
    }
}

extern "C" void kernel_launch(void* const* d_in, const int* in_sizes, int n_in,
                              void* d_out, int out_size, void* d_ws, size_t ws_size,
                              hipStream_t stream) {
    const float* x     = (const float*)d_in[0];
    const int*   ei    = (const int*)d_in[1];
    const int*   batch = (const int*)d_in[2];
    const float* W1 = (const float*)d_in[3];  const float* b1 = (const float*)d_in[4];
    const float* W2 = (const float*)d_in[5];  const float* b2 = (const float*)d_in[6];
    const float* W3 = (const float*)d_in[7];  const float* b3 = (const float*)d_in[8];
    const float* W4 = (const float*)d_in[9];  const float* b4 = (const float*)d_in[10];
    const float* Wf1 = (const float*)d_in[11]; const float* bf1 = (const float*)d_in[12];
    const float* Wf2 = (const float*)d_in[13]; const float* bf2 = (const float*)d_in[14];
    float* out = (float*)d_out;

    int N = in_sizes[0] / 32;   // 100000
    int E = in_sizes[1] / 2;    // 1600000
    int G = out_size;           // 2048
    const int* src = ei;
    const int* dst = ei + E;

    // Workspace layout (~92 MB)
    char* ws = (char*)d_ws;
    size_t off = 0;
    auto alloc = [&](size_t bytes) -> void* {
        void* p = (void*)(ws + off);
        off += (bytes + 255) & ~(size_t)255;
        return p;
    };
    int*   degcnt = (int*)alloc((size_t)N * 4);
    float* dinv   = (float*)alloc((size_t)N * 4);
    int*   rowptr = (int*)alloc((size_t)(N + 1) * 4);
    int*   bsum   = (int*)alloc((size_t)128 * 4);
    int*   col    = (int*)alloc((size_t)E * 4);
    float* val    = (float*)alloc((size_t)E * 4);
    float* bufA   = (float*)alloc((size_t)N * HIDDEN * 4);
    float* bufB   = (float*)alloc((size_t)N * HIDDEN * 4);
    float* gbuf   = (float*)alloc((size_t)G * HIDDEN * 4);
    (void)ws_size;

    // epos (E ints) aliases bufA: dead after fill_csr, before aggX written.
    int* epos = (int*)bufA;
    // aggX (N x 32) also lives in bufA: written after fill_csr completes.
    float* aggX = bufA;

    int gN   = (N + 255) / 256;
    int gE   = (E + 255) / 256;
    int gAgg32 = (int)(((long long)N * 4 + 255) / 256);
    int gAgg96 = (int)(((long long)N * 12 + 255) / 256);
    int nb   = (N + 1023) / 1024;   // 98 scan blocks (<= 128)

    // ---- CSR build (once per call) ----
    zero_int_kernel<<<gN, 256, 0, stream>>>(degcnt, N);
    deg_pos_kernel<<<gE, 256, 0, stream>>>(dst, degcnt, epos, E);
    dinv_kernel<<<gN, 256, 0, stream>>>(degcnt, dinv, N);
    scan_reduce_kernel<<<nb, 256, 0, stream>>>(degcnt, bsum, N);
    scan_bsum_kernel<<<1, 128, 0, stream>>>(bsum, nb);
    scan_write_kernel<<<nb, 256, 0, stream>>>(degcnt, bsum, rowptr, N, E);
    fill_csr_kernel<<<gE, 256, 0, stream>>>(src, dst, epos, dinv, rowptr, col, val, E);

    // ---- layer 1 reassociated: aggX = Â X (32 feats), then (aggX)W1 + b1 ----
    aggregate_kernel<4, 2, false, false><<<gAgg32, 256, 0, stream>>>(
        x, rowptr, col, val, dinv, nullptr, aggX, nullptr, nullptr, N);
    gemm_kernel<32, false, true><<<gN, 256, 0, stream>>>(aggX, W1, b1, bufB, N);

    // ---- layers 2-3: xw = relu(h) W; h' = Â xw + b ----
    gemm_kernel<96, true, false><<<gN, 256, 0, stream>>>(bufB, W2, nullptr, bufA, N);
    aggregate_kernel<12, 2, false, true><<<gAgg96, 256, 0, stream>>>(
        bufA, rowptr, col, val, dinv, b2, bufB, nullptr, nullptr, N);

    gemm_kernel<96, true, false><<<gN, 256, 0, stream>>>(bufB, W3, nullptr, bufA, N);
    aggregate_kernel<12, 2, false, true><<<gAgg96, 256, 0, stream>>>(
        bufA, rowptr, col, val, dinv, b3, bufB, nullptr, nullptr, N);

    // ---- layer 4: aggregate fused with relu + global_add_pool ----
    zero_kernel<<<(G * HIDDEN + 255) / 256, 256, 0, stream>>>(gbuf, G * HIDDEN);
    gemm_kernel<96, true, false><<<gN, 256, 0, stream>>>(bufB, W4, nullptr, bufA, N);
    aggregate_kernel<12, 2, true, true><<<gAgg96, 256, 0, stream>>>(
        bufA, rowptr, col, val, dinv, b4, nullptr, batch, gbuf, N);

    // ---- MLP head ----
    mlp_kernel<<<G, 64, 0, stream>>>(gbuf, Wf1, bf1, Wf2, bf2, out, G);
}

// Round 5
// 704.751 us; speedup vs baseline: 12.0915x; 1.2087x over previous
//
#include <hip/hip_runtime.h>
#include <hip/hip_fp16.h>

// GCN: 4x GCNConv(relu) -> global_add_pool -> MLP(96->32 relu ->1)
// N=100000 nodes, E=1600000 edges, F=32, H=96, G=2048 graphs.
//
// R5: gather operand (xw) stored fp16 (halves gather bytes; fp32 accumulate;
// error ~1e-3 << 3.84e-2 threshold). Aggregate loop reverted to R3 shape
// (TPN threads/node, 1 value/thread, 4-way unroll) after R4's TPN=12/VPT=2
// regressed via wave divergence. Layer-1 reassociation (Â X)W1 kept.

#define HIDDEN 96

__device__ inline float4 h4_to_f4(uint2 u) {
    __half2 a = *reinterpret_cast<__half2*>(&u.x);
    __half2 b = *reinterpret_cast<__half2*>(&u.y);
    float2 fa = __half22float2(a), fb = __half22float2(b);
    return make_float4(fa.x, fa.y, fb.x, fb.y);
}

__device__ inline uint2 f4_to_h4(float4 v) {
    __half2 a = __float22half2_rn(make_float2(v.x, v.y));
    __half2 b = __float22half2_rn(make_float2(v.z, v.w));
    uint2 u;
    u.x = *reinterpret_cast<unsigned*>(&a);
    u.y = *reinterpret_cast<unsigned*>(&b);
    return u;
}

__global__ __launch_bounds__(256) void zero_int_kernel(int* p, int n) {
    int i = blockIdx.x * 256 + threadIdx.x;
    if (i < n) p[i] = 0;
}

__global__ __launch_bounds__(256) void zero_kernel(float* p, int n) {
    int i = blockIdx.x * 256 + threadIdx.x;
    if (i < n) p[i] = 0.0f;
}

// cast fp32 -> fp16, float4 granularity (n4 = count of float4s)
__global__ __launch_bounds__(256) void cast_h_kernel(const float4* __restrict__ in,
                                                     uint2* __restrict__ out, int n4) {
    int i = blockIdx.x * 256 + threadIdx.x;
    if (i < n4) out[i] = f4_to_h4(in[i]);
}

// in-degree histogram over dst; epos[e] = this edge's slot within its dst row
__global__ __launch_bounds__(256) void deg_pos_kernel(const int* __restrict__ dst,
                                                      int* __restrict__ cnt,
                                                      int* __restrict__ epos, int E) {
    int e = blockIdx.x * 256 + threadIdx.x;
    if (e < E) epos[e] = atomicAdd(&cnt[dst[e]], 1);
}

__global__ __launch_bounds__(256) void dinv_kernel(const int* __restrict__ cnt,
                                                   float* __restrict__ dinv, int n) {
    int i = blockIdx.x * 256 + threadIdx.x;
    if (i < n) dinv[i] = rsqrtf((float)(cnt[i] + 1));
}

// ---- 3-phase multi-block exclusive scan of cnt[0..N) -> rowptr ----
__global__ __launch_bounds__(256) void scan_reduce_kernel(const int* __restrict__ cnt,
                                                          int* __restrict__ bsum, int N) {
    __shared__ int s[256];
    int b = blockIdx.x, tid = threadIdx.x;
    int base = b * 1024;
    int v = 0;
    for (int j = tid; j < 1024; j += 256) {
        int i = base + j;
        v += (i < N) ? cnt[i] : 0;
    }
    s[tid] = v;
    __syncthreads();
    for (int off = 128; off > 0; off >>= 1) {
        if (tid < off) s[tid] += s[tid + off];
        __syncthreads();
    }
    if (tid == 0) bsum[b] = s[0];
}

__global__ __launch_bounds__(128) void scan_bsum_kernel(int* __restrict__ bsum, int nb) {
    __shared__ int s[128];
    int tid = threadIdx.x;
    int v = (tid < nb) ? bsum[tid] : 0;
    s[tid] = v;
    __syncthreads();
    for (int off = 1; off < 128; off <<= 1) {
        int t = (tid >= off) ? s[tid - off] : 0;
        __syncthreads();
        s[tid] += t;
        __syncthreads();
    }
    if (tid < nb) bsum[tid] = s[tid] - v;  // exclusive
}

__global__ __launch_bounds__(256) void scan_write_kernel(const int* __restrict__ cnt,
                                                         const int* __restrict__ bsum,
                                                         int* __restrict__ rowptr,
                                                         int N, int E) {
    __shared__ int ts[256];
    int b = blockIdx.x, tid = threadIdx.x;
    int base = b * 1024 + tid * 4;
    int v0 = (base + 0 < N) ? cnt[base + 0] : 0;
    int v1 = (base + 1 < N) ? cnt[base + 1] : 0;
    int v2 = (base + 2 < N) ? cnt[base + 2] : 0;
    int v3 = (base + 3 < N) ? cnt[base + 3] : 0;
    int sum = v0 + v1 + v2 + v3;
    ts[tid] = sum;
    __syncthreads();
    for (int off = 1; off < 256; off <<= 1) {
        int t = (tid >= off) ? ts[tid - off] : 0;
        __syncthreads();
        ts[tid] += t;
        __syncthreads();
    }
    int excl = bsum[b] + ts[tid] - sum;
    if (base + 0 < N) rowptr[base + 0] = excl;
    if (base + 1 < N) rowptr[base + 1] = excl + v0;
    if (base + 2 < N) rowptr[base + 2] = excl + v0 + v1;
    if (base + 3 < N) rowptr[base + 3] = excl + v0 + v1 + v2;
    if (b == 0 && tid == 0) rowptr[N] = E;
}

// Fill CSR slots (no atomics: slot position precomputed in epos).
__global__ __launch_bounds__(256) void fill_csr_kernel(const int* __restrict__ src,
                                                       const int* __restrict__ dst,
                                                       const int* __restrict__ epos,
                                                       const float* __restrict__ dinv,
                                                       const int* __restrict__ rowptr,
                                                       int* __restrict__ col,
                                                       float* __restrict__ val, int E) {
    int e = blockIdx.x * 256 + threadIdx.x;
    if (e >= E) return;
    int s = src[e];
    int d = dst[e];
    int idx = rowptr[d] + epos[e];
    col[idx] = s;
    val[idx] = dinv[s] * dinv[d];
}

// Y[n x 96] = act(X[n x K]) @ W[K x 96] (+ b).  W in LDS (broadcast reads),
// one row per thread, 24 float4 accumulators. HALF_OUT: store Y as fp16.
template <int K, bool RELU, bool BIAS, bool HALF_OUT>
__global__ __launch_bounds__(256) void gemm_kernel(const float* __restrict__ X,
                                                   const float* __restrict__ W,
                                                   const float* __restrict__ b,
                                                   void* __restrict__ Y, int n) {
    __shared__ float wlds[K * HIDDEN];
    for (int idx = threadIdx.x; idx < K * HIDDEN; idx += 256) wlds[idx] = W[idx];
    __syncthreads();

    int row = blockIdx.x * 256 + threadIdx.x;
    if (row >= n) return;

    float4 acc[24];
#pragma unroll
    for (int j = 0; j < 24; j++) acc[j] = make_float4(0.f, 0.f, 0.f, 0.f);

    const float4* wl4 = reinterpret_cast<const float4*>(wlds);
    const float4* xrow = reinterpret_cast<const float4*>(X + (size_t)row * K);

    for (int k0 = 0; k0 < K; k0 += 4) {
        float4 xv = xrow[k0 >> 2];
        if (RELU) {
            xv.x = fmaxf(xv.x, 0.f); xv.y = fmaxf(xv.y, 0.f);
            xv.z = fmaxf(xv.z, 0.f); xv.w = fmaxf(xv.w, 0.f);
        }
#pragma unroll
        for (int kk = 0; kk < 4; kk++) {
            float xs = (kk == 0) ? xv.x : (kk == 1) ? xv.y : (kk == 2) ? xv.z : xv.w;
#pragma unroll
            for (int j = 0; j < 24; j++) {
                float4 w = wl4[(k0 + kk) * 24 + j];
                acc[j].x += xs * w.x;
                acc[j].y += xs * w.y;
                acc[j].z += xs * w.z;
                acc[j].w += xs * w.w;
            }
        }
    }

#pragma unroll
    for (int j = 0; j < 24; j++) {
        if (BIAS) {
            float4 bb = reinterpret_cast<const float4*>(b)[j];
            acc[j].x += bb.x; acc[j].y += bb.y; acc[j].z += bb.z; acc[j].w += bb.w;
        }
    }
    if (HALF_OUT) {
        uint2* y2 = reinterpret_cast<uint2*>(Y) + (size_t)row * 24;
#pragma unroll
        for (int j = 0; j < 24; j++) y2[j] = f4_to_h4(acc[j]);
    } else {
        float4* y4 = reinterpret_cast<float4*>(Y) + (size_t)row * 24;
#pragma unroll
        for (int j = 0; j < 24; j++) y4[j] = acc[j];
    }
}

// out[i] = dinv[i]^2*xw[i] (+ b) + sum_e val[e]*xw[col[e]], xw in fp16.
// TPN threads/node, each owns 4 features (one uint2 = 8B load), 4-way edge
// unroll -> 4 outstanding dwordx2 gathers/thread. fp32 accumulate.
// POOL: atomicAdd relu(acc) into gpool[batch[i]] instead of writing out.
template <int TPN, bool POOL, bool BIAS>
__global__ __launch_bounds__(256) void aggregate_kernel(const uint2* __restrict__ xwh,
                                                        const int* __restrict__ rowptr,
                                                        const int* __restrict__ col,
                                                        const float* __restrict__ val,
                                                        const float* __restrict__ dinv,
                                                        const float* __restrict__ b,
                                                        float* __restrict__ out,
                                                        const int* __restrict__ batch,
                                                        float* __restrict__ gpool, int n) {
    unsigned t = blockIdx.x * 256 + threadIdx.x;
    unsigned i = t / (unsigned)TPN, q = t % (unsigned)TPN;
    if (i >= (unsigned)n) return;

    float dv = dinv[i];
    float s = dv * dv;
    float4 self = h4_to_f4(xwh[i * TPN + q]);
    float4 acc = make_float4(s * self.x, s * self.y, s * self.z, s * self.w);
    if (BIAS) {
        float4 bb = reinterpret_cast<const float4*>(b)[q];
        acc.x += bb.x; acc.y += bb.y; acc.z += bb.z; acc.w += bb.w;
    }

    int e = rowptr[i], end = rowptr[i + 1];
    for (; e + 3 < end; e += 4) {
        int c0 = col[e], c1 = col[e + 1], c2 = col[e + 2], c3 = col[e + 3];
        float w0 = val[e], w1 = val[e + 1], w2 = val[e + 2], w3 = val[e + 3];
        uint2 u0 = xwh[(unsigned)c0 * TPN + q];
        uint2 u1 = xwh[(unsigned)c1 * TPN + q];
        uint2 u2 = xwh[(unsigned)c2 * TPN + q];
        uint2 u3 = xwh[(unsigned)c3 * TPN + q];
        float4 v0 = h4_to_f4(u0), v1 = h4_to_f4(u1);
        float4 v2 = h4_to_f4(u2), v3 = h4_to_f4(u3);
        acc.x += w0 * v0.x + w1 * v1.x + w2 * v2.x + w3 * v3.x;
        acc.y += w0 * v0.y + w1 * v1.y + w2 * v2.y + w3 * v3.y;
        acc.z += w0 * v0.z + w1 * v1.z + w2 * v2.z + w3 * v3.z;
        acc.w += w0 * v0.w + w1 * v1.w + w2 * v2.w + w3 * v3.w;
    }
    for (; e < end; e++) {
        int c0 = col[e];
        float w0 = val[e];
        float4 g = h4_to_f4(xwh[(unsigned)c0 * TPN + q]);
        acc.x += w0 * g.x; acc.y += w0 * g.y;
        acc.z += w0 * g.z; acc.w += w0 * g.w;
    }

    if (POOL) {
        float* o = gpool + (size_t)batch[i] * (TPN * 4);
        unsigned fo = q * 4u;
        atomicAdd(o + fo + 0, fmaxf(acc.x, 0.f));
        atomicAdd(o + fo + 1, fmaxf(acc.y, 0.f));
        atomicAdd(o + fo + 2, fmaxf(acc.z, 0.f));
        atomicAdd(o + fo + 3, fmaxf(acc.w, 0.f));
    } else {
        reinterpret_cast<float4*>(out)[i * TPN + q] = acc;
    }
}

__global__ __launch_bounds__(64) void mlp_kernel(const float* __restrict__ g,
                                                 const float* __restrict__ Wf1,
                                                 const float* __restrict__ bf1,
                                                 const float* __restrict__ Wf2,
                                                 const float* __restrict__ bf2,
                                                 float* __restrict__ out, int G) {
    __shared__ float gs[HIDDEN];
    __shared__ float hid[32];
    int blk = blockIdx.x;
    int lane = threadIdx.x;
    for (int idx = lane; idx < HIDDEN; idx += 64) gs[idx] = g[(size_t)blk * HIDDEN + idx];
    __syncthreads();
    if (lane < 32) {
        float a = bf1[lane];
        for (int k = 0; k < HIDDEN; k++) a = fmaf(gs[k], Wf1[k * 32 + lane], a);
        hid[lane] = fmaxf(a, 0.f);
    }
    __syncthreads();
    if (lane == 0) {
        float o = bf2[0];
        for (int k = 0; k < 32; k++) o = fmaf(hid[k], Wf2[k], o);
        out[blk] = o;
    }
}

extern "C" void kernel_launch(void* const* d_in, const int* in_sizes, int n_in,
                              void* d_out, int out_size, void* d_ws, size_t ws_size,
                              hipStream_t stream) {
    const float* x     = (const float*)d_in[0];
    const int*   ei    = (const int*)d_in[1];
    const int*   batch = (const int*)d_in[2];
    const float* W1 = (const float*)d_in[3];  const float* b1 = (const float*)d_in[4];
    const float* W2 = (const float*)d_in[5];  const float* b2 = (const float*)d_in[6];
    const float* W3 = (const float*)d_in[7];  const float* b3 = (const float*)d_in[8];
    const float* W4 = (const float*)d_in[9];  const float* b4 = (const float*)d_in[10];
    const float* Wf1 = (const float*)d_in[11]; const float* bf1 = (const float*)d_in[12];
    const float* Wf2 = (const float*)d_in[13]; const float* bf2 = (const float*)d_in[14];
    float* out = (float*)d_out;

    int N = in_sizes[0] / 32;   // 100000
    int E = in_sizes[1] / 2;    // 1600000
    int G = out_size;           // 2048
    const int* src = ei;
    const int* dst = ei + E;

    // Workspace layout (~91 MB)
    char* ws = (char*)d_ws;
    size_t off = 0;
    auto alloc = [&](size_t bytes) -> void* {
        void* p = (void*)(ws + off);
        off += (bytes + 255) & ~(size_t)255;
        return p;
    };
    int*   degcnt = (int*)alloc((size_t)N * 4);
    float* dinv   = (float*)alloc((size_t)N * 4);
    int*   rowptr = (int*)alloc((size_t)(N + 1) * 4);
    int*   bsum   = (int*)alloc((size_t)128 * 4);
    int*   col    = (int*)alloc((size_t)E * 4);
    float* val    = (float*)alloc((size_t)E * 4);
    float* bufA   = (float*)alloc((size_t)N * 32 * 4);      // aggX (+ epos alias)
    float* bufB   = (float*)alloc((size_t)N * HIDDEN * 4);  // h (fp32)
    uint2* bufH   = (uint2*)alloc((size_t)N * HIDDEN * 2);  // xw (fp16)
    uint2* xh     = (uint2*)alloc((size_t)N * 32 * 2);      // x cast fp16
    float* gbuf   = (float*)alloc((size_t)G * HIDDEN * 4);
    (void)ws_size;

    // epos (E ints = 6.4MB) aliases bufA (12.8MB): dead after fill_csr,
    // before aggX is written.
    int* epos = (int*)bufA;
    float* aggX = bufA;

    int gN   = (N + 255) / 256;
    int gE   = (E + 255) / 256;
    int gAgg32 = (int)(((long long)N * 8 + 255) / 256);
    int gAgg96 = (int)(((long long)N * 24 + 255) / 256);
    int nb   = (N + 1023) / 1024;   // 98 scan blocks (<= 128)

    // ---- CSR build (once per call) ----
    zero_int_kernel<<<gN, 256, 0, stream>>>(degcnt, N);
    deg_pos_kernel<<<gE, 256, 0, stream>>>(dst, degcnt, epos, E);
    dinv_kernel<<<gN, 256, 0, stream>>>(degcnt, dinv, N);
    scan_reduce_kernel<<<nb, 256, 0, stream>>>(degcnt, bsum, N);
    scan_bsum_kernel<<<1, 128, 0, stream>>>(bsum, nb);
    scan_write_kernel<<<nb, 256, 0, stream>>>(degcnt, bsum, rowptr, N, E);
    fill_csr_kernel<<<gE, 256, 0, stream>>>(src, dst, epos, dinv, rowptr, col, val, E);

    // ---- layer 1 reassociated: aggX = Â x (32 feats, fp16 gather), then
    //      h1 = (aggX) W1 + b1 ----
    cast_h_kernel<<<(N * 8 + 255) / 256, 256, 0, stream>>>(
        reinterpret_cast<const float4*>(x), xh, N * 8);
    aggregate_kernel<8, false, false><<<gAgg32, 256, 0, stream>>>(
        xh, rowptr, col, val, dinv, nullptr, aggX, nullptr, nullptr, N);
    gemm_kernel<32, false, true, false><<<gN, 256, 0, stream>>>(aggX, W1, b1, bufB, N);

    // ---- layers 2-3: xw = relu(h) W (fp16); h' = Â xw + b (fp32) ----
    gemm_kernel<96, true, false, true><<<gN, 256, 0, stream>>>(bufB, W2, nullptr, bufH, N);
    aggregate_kernel<24, false, true><<<gAgg96, 256, 0, stream>>>(
        bufH, rowptr, col, val, dinv, b2, bufB, nullptr, nullptr, N);

    gemm_kernel<96, true, false, true><<<gN, 256, 0, stream>>>(bufB, W3, nullptr, bufH, N);
    aggregate_kernel<24, false, true><<<gAgg96, 256, 0, stream>>>(
        bufH, rowptr, col, val, dinv, b3, bufB, nullptr, nullptr, N);

    // ---- layer 4: aggregate fused with relu + global_add_pool ----
    zero_kernel<<<(G * HIDDEN + 255) / 256, 256, 0, stream>>>(gbuf, G * HIDDEN);
    gemm_kernel<96, true, false, true><<<gN, 256, 0, stream>>>(bufB, W4, nullptr, bufH, N);
    aggregate_kernel<24, true, true><<<gAgg96, 256, 0, stream>>>(
        bufH, rowptr, col, val, dinv, b4, nullptr, batch, gbuf, N);

    // ---- MLP head ----
    mlp_kernel<<<G, 64, 0, stream>>>(gbuf, Wf1, bf1, Wf2, bf2, out, G);
}

// Round 6
// 696.505 us; speedup vs baseline: 12.2346x; 1.0118x over previous
//
#include <hip/hip_runtime.h>
#include <hip/hip_fp16.h>

// GCN: 4x GCNConv(relu) -> global_add_pool -> MLP(96->32 relu ->1)
// N=100000 nodes, E=1600000 edges, F=32, H=96, G=2048 graphs.
//
// R6: all inter-layer buffers fp16 (gather operand AND h; fp32 accumulate).
// CSR rows padded to multiples of 8 (col=0,val=0 slots) -> 32B-aligned rows,
// int4/float4 col/val loads, 8-way edge unroll = 8 outstanding gathers/thread.
// Layer-1 reassociation (A X)W1 and layer-4 agg+relu+pool fusion kept.

#define HIDDEN 96

__device__ inline float4 h4_to_f4(uint2 u) {
    __half2 a = *reinterpret_cast<__half2*>(&u.x);
    __half2 b = *reinterpret_cast<__half2*>(&u.y);
    float2 fa = __half22float2(a), fb = __half22float2(b);
    return make_float4(fa.x, fa.y, fb.x, fb.y);
}

__device__ inline uint2 f4_to_h4(float4 v) {
    __half2 a = __float22half2_rn(make_float2(v.x, v.y));
    __half2 b = __float22half2_rn(make_float2(v.z, v.w));
    uint2 u;
    u.x = *reinterpret_cast<unsigned*>(&a);
    u.y = *reinterpret_cast<unsigned*>(&b);
    return u;
}

__device__ inline int pad8(int c) { return (c + 7) & ~7; }

__global__ __launch_bounds__(256) void zero_int_kernel(int* p, int n) {
    int i = blockIdx.x * 256 + threadIdx.x;
    if (i < n) p[i] = 0;
}

__global__ __launch_bounds__(256) void zero_kernel(float* p, int n) {
    int i = blockIdx.x * 256 + threadIdx.x;
    if (i < n) p[i] = 0.0f;
}

// cast fp32 -> fp16, float4 granularity (n4 = count of float4s)
__global__ __launch_bounds__(256) void cast_h_kernel(const float4* __restrict__ in,
                                                     uint2* __restrict__ out, int n4) {
    int i = blockIdx.x * 256 + threadIdx.x;
    if (i < n4) out[i] = f4_to_h4(in[i]);
}

// in-degree histogram over dst; epos[e] = this edge's slot within its dst row
__global__ __launch_bounds__(256) void deg_pos_kernel(const int* __restrict__ dst,
                                                      int* __restrict__ cnt,
                                                      int* __restrict__ epos, int E) {
    int e = blockIdx.x * 256 + threadIdx.x;
    if (e < E) epos[e] = atomicAdd(&cnt[dst[e]], 1);
}

__global__ __launch_bounds__(256) void dinv_kernel(const int* __restrict__ cnt,
                                                   float* __restrict__ dinv, int n) {
    int i = blockIdx.x * 256 + threadIdx.x;
    if (i < n) dinv[i] = rsqrtf((float)(cnt[i] + 1));
}

// ---- 3-phase multi-block exclusive scan of pad8(cnt[0..N)) -> rowptr ----
__global__ __launch_bounds__(256) void scan_reduce_kernel(const int* __restrict__ cnt,
                                                          int* __restrict__ bsum, int N) {
    __shared__ int s[256];
    int b = blockIdx.x, tid = threadIdx.x;
    int base = b * 1024;
    int v = 0;
    for (int j = tid; j < 1024; j += 256) {
        int i = base + j;
        v += (i < N) ? pad8(cnt[i]) : 0;
    }
    s[tid] = v;
    __syncthreads();
    for (int off = 128; off > 0; off >>= 1) {
        if (tid < off) s[tid] += s[tid + off];
        __syncthreads();
    }
    if (tid == 0) bsum[b] = s[0];
}

__global__ __launch_bounds__(128) void scan_bsum_kernel(int* __restrict__ bsum, int nb) {
    __shared__ int s[128];
    int tid = threadIdx.x;
    int v = (tid < nb) ? bsum[tid] : 0;
    s[tid] = v;
    __syncthreads();
    for (int off = 1; off < 128; off <<= 1) {
        int t = (tid >= off) ? s[tid - off] : 0;
        __syncthreads();
        s[tid] += t;
        __syncthreads();
    }
    if (tid < nb) bsum[tid] = s[tid] - v;  // exclusive
}

// writes rowptr[0..N]; rowptr[N] = padded total (falls out of the scan)
__global__ __launch_bounds__(256) void scan_write_kernel(const int* __restrict__ cnt,
                                                         const int* __restrict__ bsum,
                                                         int* __restrict__ rowptr, int N) {
    __shared__ int ts[256];
    int b = blockIdx.x, tid = threadIdx.x;
    int base = b * 1024 + tid * 4;
    int v0 = (base + 0 < N) ? pad8(cnt[base + 0]) : 0;
    int v1 = (base + 1 < N) ? pad8(cnt[base + 1]) : 0;
    int v2 = (base + 2 < N) ? pad8(cnt[base + 2]) : 0;
    int v3 = (base + 3 < N) ? pad8(cnt[base + 3]) : 0;
    int sum = v0 + v1 + v2 + v3;
    ts[tid] = sum;
    __syncthreads();
    for (int off = 1; off < 256; off <<= 1) {
        int t = (tid >= off) ? ts[tid - off] : 0;
        __syncthreads();
        ts[tid] += t;
        __syncthreads();
    }
    int excl = bsum[b] + ts[tid] - sum;
    if (base + 0 <= N) rowptr[base + 0] = excl;
    if (base + 1 <= N) rowptr[base + 1] = excl + v0;
    if (base + 2 <= N) rowptr[base + 2] = excl + v0 + v1;
    if (base + 3 <= N) rowptr[base + 3] = excl + v0 + v1 + v2;
}

// Fill CSR slots (no atomics: slot position precomputed in epos).
// Padding slots stay col=0,val=0 (pre-zeroed) -> contribute exactly 0.
__global__ __launch_bounds__(256) void fill_csr_kernel(const int* __restrict__ src,
                                                       const int* __restrict__ dst,
                                                       const int* __restrict__ epos,
                                                       const float* __restrict__ dinv,
                                                       const int* __restrict__ rowptr,
                                                       int* __restrict__ col,
                                                       float* __restrict__ val, int E) {
    int e = blockIdx.x * 256 + threadIdx.x;
    if (e >= E) return;
    int s = src[e];
    int d = dst[e];
    int idx = rowptr[d] + epos[e];
    col[idx] = s;
    val[idx] = dinv[s] * dinv[d];
}

// Y[n x 96] = act(X[n x K]) @ W[K x 96] (+ b).  W in LDS (broadcast reads),
// one row per thread, 24 float4 accumulators. X and Y in fp16 (fp32 math).
template <int K, bool RELU, bool BIAS>
__global__ __launch_bounds__(256) void gemm_kernel(const uint2* __restrict__ X,
                                                   const float* __restrict__ W,
                                                   const float* __restrict__ b,
                                                   uint2* __restrict__ Y, int n) {
    __shared__ float wlds[K * HIDDEN];
    for (int idx = threadIdx.x; idx < K * HIDDEN; idx += 256) wlds[idx] = W[idx];
    __syncthreads();

    int row = blockIdx.x * 256 + threadIdx.x;
    if (row >= n) return;

    float4 acc[24];
#pragma unroll
    for (int j = 0; j < 24; j++) acc[j] = make_float4(0.f, 0.f, 0.f, 0.f);

    const float4* wl4 = reinterpret_cast<const float4*>(wlds);
    const uint2* xrow = X + (size_t)row * (K / 4);

    for (int k0 = 0; k0 < K; k0 += 4) {
        float4 xv = h4_to_f4(xrow[k0 >> 2]);
        if (RELU) {
            xv.x = fmaxf(xv.x, 0.f); xv.y = fmaxf(xv.y, 0.f);
            xv.z = fmaxf(xv.z, 0.f); xv.w = fmaxf(xv.w, 0.f);
        }
#pragma unroll
        for (int kk = 0; kk < 4; kk++) {
            float xs = (kk == 0) ? xv.x : (kk == 1) ? xv.y : (kk == 2) ? xv.z : xv.w;
#pragma unroll
            for (int j = 0; j < 24; j++) {
                float4 w = wl4[(k0 + kk) * 24 + j];
                acc[j].x += xs * w.x;
                acc[j].y += xs * w.y;
                acc[j].z += xs * w.z;
                acc[j].w += xs * w.w;
            }
        }
    }

    uint2* y2 = Y + (size_t)row * 24;
#pragma unroll
    for (int j = 0; j < 24; j++) {
        if (BIAS) {
            float4 bb = reinterpret_cast<const float4*>(b)[j];
            acc[j].x += bb.x; acc[j].y += bb.y; acc[j].z += bb.z; acc[j].w += bb.w;
        }
        y2[j] = f4_to_h4(acc[j]);
    }
}

// out[i] = dinv[i]^2*xw[i] (+ b) + sum_e val[e]*xw[col[e]], xw fp16.
// TPN threads/node (4 feats each), rows padded to 8 edges -> aligned
// int4/float4 col/val loads, 8-way unroll = 8 outstanding 8B gathers/thread.
// fp32 accumulate. POOL: atomicAdd relu(acc) into gpool[batch[i]] (fp32);
// else store fp16 h into out.
template <int TPN, bool POOL, bool BIAS>
__global__ __launch_bounds__(256) void aggregate_kernel(const uint2* __restrict__ xwh,
                                                        const int* __restrict__ rowptr,
                                                        const int* __restrict__ col,
                                                        const float* __restrict__ val,
                                                        const float* __restrict__ dinv,
                                                        const float* __restrict__ b,
                                                        uint2* __restrict__ out,
                                                        const int* __restrict__ batch,
                                                        float* __restrict__ gpool, int n) {
    unsigned t = blockIdx.x * 256 + threadIdx.x;
    unsigned i = t / (unsigned)TPN, q = t % (unsigned)TPN;
    if (i >= (unsigned)n) return;

    float dv = dinv[i];
    float s = dv * dv;
    float4 self = h4_to_f4(xwh[i * TPN + q]);
    float4 acc = make_float4(s * self.x, s * self.y, s * self.z, s * self.w);
    if (BIAS) {
        float4 bb = reinterpret_cast<const float4*>(b)[q];
        acc.x += bb.x; acc.y += bb.y; acc.z += bb.z; acc.w += bb.w;
    }

    int e = rowptr[i], end = rowptr[i + 1];
    for (; e < end; e += 8) {
        int4 ca = *reinterpret_cast<const int4*>(col + e);
        int4 cb = *reinterpret_cast<const int4*>(col + e + 4);
        float4 wa = *reinterpret_cast<const float4*>(val + e);
        float4 wb = *reinterpret_cast<const float4*>(val + e + 4);
        uint2 u0 = xwh[(unsigned)ca.x * TPN + q];
        uint2 u1 = xwh[(unsigned)ca.y * TPN + q];
        uint2 u2 = xwh[(unsigned)ca.z * TPN + q];
        uint2 u3 = xwh[(unsigned)ca.w * TPN + q];
        uint2 u4 = xwh[(unsigned)cb.x * TPN + q];
        uint2 u5 = xwh[(unsigned)cb.y * TPN + q];
        uint2 u6 = xwh[(unsigned)cb.z * TPN + q];
        uint2 u7 = xwh[(unsigned)cb.w * TPN + q];
        float4 v0 = h4_to_f4(u0), v1 = h4_to_f4(u1);
        float4 v2 = h4_to_f4(u2), v3 = h4_to_f4(u3);
        float4 v4 = h4_to_f4(u4), v5 = h4_to_f4(u5);
        float4 v6 = h4_to_f4(u6), v7 = h4_to_f4(u7);
        acc.x += wa.x * v0.x + wa.y * v1.x + wa.z * v2.x + wa.w * v3.x
               + wb.x * v4.x + wb.y * v5.x + wb.z * v6.x + wb.w * v7.x;
        acc.y += wa.x * v0.y + wa.y * v1.y + wa.z * v2.y + wa.w * v3.y
               + wb.x * v4.y + wb.y * v5.y + wb.z * v6.y + wb.w * v7.y;
        acc.z += wa.x * v0.z + wa.y * v1.z + wa.z * v2.z + wa.w * v3.z
               + wb.x * v4.z + wb.y * v5.z + wb.z * v6.z + wb.w * v7.z;
        acc.w += wa.x * v0.w + wa.y * v1.w + wa.z * v2.w + wa.w * v3.w
               + wb.x * v4.w + wb.y * v5.w + wb.z * v6.w + wb.w * v7.w;
    }

    if (POOL) {
        float* o = gpool + (size_t)batch[i] * (TPN * 4);
        unsigned fo = q * 4u;
        atomicAdd(o + fo + 0, fmaxf(acc.x, 0.f));
        atomicAdd(o + fo + 1, fmaxf(acc.y, 0.f));
        atomicAdd(o + fo + 2, fmaxf(acc.z, 0.f));
        atomicAdd(o + fo + 3, fmaxf(acc.w, 0.f));
    } else {
        out[i * TPN + q] = f4_to_h4(acc);
    }
}

__global__ __launch_bounds__(64) void mlp_kernel(const float* __restrict__ g,
                                                 const float* __restrict__ Wf1,
                                                 const float* __restrict__ bf1,
                                                 const float* __restrict__ Wf2,
                                                 const float* __restrict__ bf2,
                                                 float* __restrict__ out, int G) {
    __shared__ float gs[HIDDEN];
    __shared__ float hid[32];
    int blk = blockIdx.x;
    int lane = threadIdx.x;
    for (int idx = lane; idx < HIDDEN; idx += 64) gs[idx] = g[(size_t)blk * HIDDEN + idx];
    __syncthreads();
    if (lane < 32) {
        float a = bf1[lane];
        for (int k = 0; k < HIDDEN; k++) a = fmaf(gs[k], Wf1[k * 32 + lane], a);
        hid[lane] = fmaxf(a, 0.f);
    }
    __syncthreads();
    if (lane == 0) {
        float o = bf2[0];
        for (int k = 0; k < 32; k++) o = fmaf(hid[k], Wf2[k], o);
        out[blk] = o;
    }
}

extern "C" void kernel_launch(void* const* d_in, const int* in_sizes, int n_in,
                              void* d_out, int out_size, void* d_ws, size_t ws_size,
                              hipStream_t stream) {
    const float* x     = (const float*)d_in[0];
    const int*   ei    = (const int*)d_in[1];
    const int*   batch = (const int*)d_in[2];
    const float* W1 = (const float*)d_in[3];  const float* b1 = (const float*)d_in[4];
    const float* W2 = (const float*)d_in[5];  const float* b2 = (const float*)d_in[6];
    const float* W3 = (const float*)d_in[7];  const float* b3 = (const float*)d_in[8];
    const float* W4 = (const float*)d_in[9];  const float* b4 = (const float*)d_in[10];
    const float* Wf1 = (const float*)d_in[11]; const float* bf1 = (const float*)d_in[12];
    const float* Wf2 = (const float*)d_in[13]; const float* bf2 = (const float*)d_in[14];
    float* out = (float*)d_out;

    int N = in_sizes[0] / 32;   // 100000
    int E = in_sizes[1] / 2;    // 1600000
    int G = out_size;           // 2048
    const int* src = ei;
    const int* dst = ei + E;
    int Emax = E + 8 * N;       // padded-CSR upper bound (2.4M)

    // Workspace layout (~80 MB)
    char* ws = (char*)d_ws;
    size_t off = 0;
    auto alloc = [&](size_t bytes) -> void* {
        void* p = (void*)(ws + off);
        off += (bytes + 255) & ~(size_t)255;
        return p;
    };
    int*   degcnt = (int*)alloc((size_t)N * 4);
    float* dinv   = (float*)alloc((size_t)N * 4);
    int*   rowptr = (int*)alloc((size_t)(N + 1) * 4);
    int*   bsum   = (int*)alloc((size_t)128 * 4);
    int*   col    = (int*)alloc((size_t)Emax * 4);
    float* val    = (float*)alloc((size_t)Emax * 4);
    int*   epos   = (int*)alloc((size_t)E * 4);
    uint2* xh     = (uint2*)alloc((size_t)N * 32 * 2);      // x fp16
    uint2* aggXh  = (uint2*)alloc((size_t)N * 32 * 2);      // (A x) fp16
    uint2* bufB   = (uint2*)alloc((size_t)N * HIDDEN * 2);  // h fp16
    uint2* bufH   = (uint2*)alloc((size_t)N * HIDDEN * 2);  // xw fp16
    float* gbuf   = (float*)alloc((size_t)G * HIDDEN * 4);
    (void)ws_size;

    int gN   = (N + 255) / 256;
    int gE   = (E + 255) / 256;
    int gEm  = (Emax + 255) / 256;
    int gAgg32 = (int)(((long long)N * 8 + 255) / 256);
    int gAgg96 = (int)(((long long)N * 24 + 255) / 256);
    int nb   = (N + 1023) / 1024;   // 98 scan blocks (<= 128)

    // ---- CSR build (once per call) ----
    zero_int_kernel<<<gN, 256, 0, stream>>>(degcnt, N);
    zero_int_kernel<<<gEm, 256, 0, stream>>>(col, Emax);
    zero_kernel<<<gEm, 256, 0, stream>>>(val, Emax);
    deg_pos_kernel<<<gE, 256, 0, stream>>>(dst, degcnt, epos, E);
    dinv_kernel<<<gN, 256, 0, stream>>>(degcnt, dinv, N);
    scan_reduce_kernel<<<nb, 256, 0, stream>>>(degcnt, bsum, N);
    scan_bsum_kernel<<<1, 128, 0, stream>>>(bsum, nb);
    scan_write_kernel<<<nb, 256, 0, stream>>>(degcnt, bsum, rowptr, N);
    fill_csr_kernel<<<gE, 256, 0, stream>>>(src, dst, epos, dinv, rowptr, col, val, E);

    // ---- layer 1 reassociated: aggX = A x (32 feats), h1 = aggX W1 + b1 ----
    cast_h_kernel<<<(N * 8 + 255) / 256, 256, 0, stream>>>(
        reinterpret_cast<const float4*>(x), xh, N * 8);
    aggregate_kernel<8, false, false><<<gAgg32, 256, 0, stream>>>(
        xh, rowptr, col, val, dinv, nullptr, aggXh, nullptr, nullptr, N);
    gemm_kernel<32, false, true><<<gN, 256, 0, stream>>>(aggXh, W1, b1, bufB, N);

    // ---- layers 2-3: xw = relu(h) W (fp16); h' = A xw + b (fp16) ----
    gemm_kernel<96, true, false><<<gN, 256, 0, stream>>>(bufB, W2, nullptr, bufH, N);
    aggregate_kernel<24, false, true><<<gAgg96, 256, 0, stream>>>(
        bufH, rowptr, col, val, dinv, b2, bufB, nullptr, nullptr, N);

    gemm_kernel<96, true, false><<<gN, 256, 0, stream>>>(bufB, W3, nullptr, bufH, N);
    aggregate_kernel<24, false, true><<<gAgg96, 256, 0, stream>>>(
        bufH, rowptr, col, val, dinv, b3, bufB, nullptr, nullptr, N);

    // ---- layer 4: aggregate fused with relu + global_add_pool (fp32) ----
    zero_kernel<<<(G * HIDDEN + 255) / 256, 256, 0, stream>>>(gbuf, G * HIDDEN);
    gemm_kernel<96, true, false><<<gN, 256, 0, stream>>>(bufB, W4, nullptr, bufH, N);
    aggregate_kernel<24, true, true><<<gAgg96, 256, 0, stream>>>(
        bufH, rowptr, col, val, dinv, b4, nullptr, batch, gbuf, N);

    // ---- MLP head ----
    mlp_kernel<<<G, 64, 0, stream>>>(gbuf, Wf1, bf1, Wf2, bf2, out, G);
}